// Round 1
// 268.595 us; speedup vs baseline: 1.0578x; 1.0578x over previous
//
#include <hip/hip_runtime.h>

// LightGCN propagation: 3x SpMM over fixed COO graph + batched dot epilogue.
// R14: part_kernel re-parallelized. R13 ran the partition in 128x512 ->
// only 8 waves/CU on half the CUs (measured 22% occupancy, 3.5% VALU,
// 15% HBM: latency-bound). Now 256 chunks x 9375 edges, 1024-thread
// blocks -> 256 blocks cover all CUs at 16 waves/CU; per-block edge
// iterations drop 37->10 per pass. Runs shrink 73->~37 edges (293B ~4.6
// lines) -- still fat enough that boundary partial-line RMW is ~+8MB,
// far from R12's 9-edge blowup. Pass 1 dst values are register-cached
// (d_c[10], statically indexed) so pass 2 skips the dst re-read + div.
// Fine sort in place per super-bucket (80KB LDS, 1024thr). spmm
// standalone at full occupancy (R11). Layer 3 batch-only (R10).
// bf16 rows (R5): compulsory fabric 8 XCD x 19.2MB/layer.

#define N_USERS 50000
#define N_ITEMS 100000
#define N_NODES 150000
#define N_EDGES 2400000
#define DIM 64
#define BATCH 4096

#define CHUNKS 256
#define CHUNK_EDGES 9375   // 256*9375 = 2400000 exact
#define PPT 10             // ceil(9375/1024) edges per thread per pass
#define KB 256             // super-buckets
#define NPB 586            // nodes per bucket; 256*586 = 150016 >= N_NODES
#define ECAP 10240         // bucket capacity: mean 9375, sigma 97 -> +8.9 sigma
#define CONVB 2344         // ceil(2400000 float4 / 1024)

typedef unsigned int uint;
typedef float v2f __attribute__((ext_vector_type(2)));

__device__ __forceinline__ uint pack_bf16(float a, float b) {
    uint ua = __float_as_uint(a), ub = __float_as_uint(b);
    ua = (ua + 0x7FFFu + ((ua >> 16) & 1u)) >> 16;   // RTNE
    ub = (ub + 0x7FFFu + ((ub >> 16) & 1u)) >> 16;
    return ua | (ub << 16);
}

__device__ __forceinline__ v2f unpack_bf16x2(uint w) {
    v2f r;
    r.x = __uint_as_float(w << 16);
    r.y = __uint_as_float(w & 0xFFFF0000u);
    return r;
}

// PART: blocks [0,CHUNKS): hist pass over dst (LDS, 2KB) -> one global
// atomicAdd per bucket reserves a fat run -> scatter pass uses
// register-cached dst + src/vals. Blocks [CHUNKS,..): fp32 -> bf16 concat t0.
__global__ __launch_bounds__(1024) void part_kernel(
        const int* __restrict__ src, const int* __restrict__ dstA,
        const float* __restrict__ vals, int* __restrict__ gcur,
        int2* __restrict__ coarse,
        const float* __restrict__ emb_user, const float* __restrict__ emb_item,
        uint2* __restrict__ t0) {
    int t = threadIdx.x;
    if (blockIdx.x >= CHUNKS) {
        int i = (blockIdx.x - CHUNKS) * 1024 + t;  // float4 index, 2.4M total
        if (i < N_NODES * DIM / 4) {
            const int userN4 = N_USERS * DIM / 4; // 800000
            float4 v;
            if (i < userN4) v = ((const float4*)emb_user)[i];
            else            v = ((const float4*)emb_item)[i - userN4];
            t0[i] = make_uint2(pack_bf16(v.x, v.y), pack_bf16(v.z, v.w));
        }
        return;
    }
    __shared__ int h[KB];
    __shared__ int cur[KB];
    int c = blockIdx.x;
    if (t < KB) h[t] = 0;
    __syncthreads();
    int base = c * CHUNK_EDGES;
    int d_c[PPT];
#pragma unroll
    for (int u = 0; u < PPT; ++u) {
        int i = t + u * 1024;
        d_c[u] = 0;
        if (i < CHUNK_EDGES) {
            int d = dstA[base + i];
            d_c[u] = d;
            atomicAdd(&h[(int)((unsigned)d / NPB)], 1);  // magic-mul div
        }
    }
    __syncthreads();
    if (t < KB) cur[t] = atomicAdd(&gcur[t], h[t]);      // reserve fat run
    __syncthreads();
#pragma unroll
    for (int u = 0; u < PPT; ++u) {
        int i = t + u * 1024;
        if (i < CHUNK_EDGES) {
            int e = base + i;
            int d = d_c[u];                              // from registers
            int b = (int)((unsigned)d / NPB);
            int dl = d - b * NPB;
            int p = atomicAdd(&cur[b], 1);
            if (p < ECAP)
                coarse[b * ECAP + p] = make_int2(src[e] | (dl << 18),
                                                 __float_as_int(vals[e]));
        }
    }
}

// P4F: per-super-bucket fine sort IN PLACE. Edges -> LDS (one read),
// histogram over 586 node counters, wave-shuffle scan, rowinfo emit,
// sorted scatter back into the same region.
__global__ __launch_bounds__(1024) void p4f_fine(int2* __restrict__ coarse,
                                                 const int* __restrict__ gcur,
                                                 uint* __restrict__ rowinfo) {
    __shared__ int2 eds[ECAP];        // 81920 B
    __shared__ int cnt[640];
    __shared__ int rs_[640];
    __shared__ int cur_[640];
    __shared__ int wsum[16];
    int k = blockIdx.x, t = threadIdx.x;
    int rbase = k * ECAP;
    int ne = min(gcur[k], ECAP);
    for (int i = t; i < ne; i += 1024) eds[i] = coarse[rbase + i];
    if (t < 640) cnt[t] = 0;
    __syncthreads();
    for (int i = t; i < ne; i += 1024)
        atomicAdd(&cnt[eds[i].x >> 18], 1);
    __syncthreads();
    int wid = t >> 6, lane = t & 63;
    if (t < 640) {                    // waves 0..9 (640 = 10*64)
        int v = cnt[t];
        int incl = v;
#pragma unroll
        for (int o = 1; o < 64; o <<= 1) {
            int add = __shfl_up(incl, o, 64);
            if (lane >= o) incl += add;
        }
        rs_[t] = incl - v;
        if (lane == 63) wsum[wid] = incl;
    }
    __syncthreads();
    if (t < 64) {
        int vv = (lane < 10) ? wsum[lane] : 0;
        int inc2 = vv;
#pragma unroll
        for (int o = 1; o < 16; o <<= 1) {
            int add = __shfl_up(inc2, o, 64);
            if (lane >= o) inc2 += add;
        }
        if (lane < 10) wsum[lane] = inc2 - vv;
    }
    __syncthreads();
    if (t < 640) rs_[t] += wsum[wid];
    __syncthreads();
    int nodes0 = k * NPB;
    int nb = min(NPB, N_NODES - nodes0);
    if (t < nb)
        rowinfo[nodes0 + t] = (uint)(rbase + rs_[t]) | ((uint)cnt[t] << 22);
    if (t < 640) cur_[t] = rs_[t];
    __syncthreads();
    for (int i = t; i < ne; i += 1024) {
        int2 ev = eds[i];
        int dl = ev.x >> 18;
        int p = atomicAdd(&cur_[dl], 1);
        coarse[rbase + p] = make_int2(ev.x & 0x3FFFF, ev.y);   // strip dl
    }
}

// SpMM over bf16 rows (128B/row). R6/R10 form: one wave per node; 8 groups
// x 8 lanes; 2x unrolled -> 16 edges in flight; shfl_xor reduce.
__global__ __launch_bounds__(256) void spmm_kernel(
        const uint* __restrict__ rowinfo, const int2* __restrict__ epair,
        const uint* __restrict__ xin, uint* __restrict__ xout) {
    int n = (blockIdx.x * 256 + threadIdx.x) >> 6;   // 150000 = 4*37500 exact
    int lane = threadIdx.x & 63;
    int g = lane >> 3;
    int l = lane & 7;
    uint ri = rowinfo[n];
    int s = (int)(ri & 0x3FFFFFu);
    int e = s + (int)(ri >> 22);
    v2f a0 = {0.f, 0.f}, a1 = {0.f, 0.f}, a2 = {0.f, 0.f}, a3 = {0.f, 0.f};
    for (int j0 = s + g; j0 < e; j0 += 16) {
        int j1 = j0 + 8;
        bool p1 = j1 < e;
        int2 ev0 = epair[j0];
        int2 ev1 = epair[p1 ? j1 : j0];
        float v0 = __int_as_float(ev0.y);
        float v1 = p1 ? __int_as_float(ev1.y) : 0.f;
        uint4 r0 = ((const uint4*)(xin + (size_t)ev0.x * 32))[l];
        uint4 r1 = ((const uint4*)(xin + (size_t)ev1.x * 32))[l];
        a0 += v0 * unpack_bf16x2(r0.x);
        a1 += v0 * unpack_bf16x2(r0.y);
        a2 += v0 * unpack_bf16x2(r0.z);
        a3 += v0 * unpack_bf16x2(r0.w);
        a0 += v1 * unpack_bf16x2(r1.x);
        a1 += v1 * unpack_bf16x2(r1.y);
        a2 += v1 * unpack_bf16x2(r1.z);
        a3 += v1 * unpack_bf16x2(r1.w);
    }
#pragma unroll
    for (int off = 8; off < 64; off <<= 1) {
        a0.x += __shfl_xor(a0.x, off, 64);
        a0.y += __shfl_xor(a0.y, off, 64);
        a1.x += __shfl_xor(a1.x, off, 64);
        a1.y += __shfl_xor(a1.y, off, 64);
        a2.x += __shfl_xor(a2.x, off, 64);
        a2.y += __shfl_xor(a2.y, off, 64);
        a3.x += __shfl_xor(a3.x, off, 64);
        a3.y += __shfl_xor(a3.y, off, 64);
    }
    if (g == 0) {
        uint4 o;
        o.x = pack_bf16(a0.x, a0.y);
        o.y = pack_bf16(a1.x, a1.y);
        o.z = pack_bf16(a2.x, a2.y);
        o.w = pack_bf16(a3.x, a3.y);
        ((uint4*)(xout + (size_t)n * 32))[l] = o;
    }
}

// Layer-3 restricted to batch rows: one wave per batch node (2*BATCH waves).
// x3[n] = sum val*x2[src]; add x0 (fp32) + x1 + x2 (bf16); store fp32 row.
__global__ __launch_bounds__(256) void batch_row_kernel(
        const int* __restrict__ users, const int* __restrict__ items,
        const float* __restrict__ emb_user, const float* __restrict__ emb_item,
        const uint* __restrict__ x1, const uint* __restrict__ x2,
        const uint* __restrict__ rowinfo, const int2* __restrict__ epair,
        float4* __restrict__ rows) {
    int w = (blockIdx.x * 256 + threadIdx.x) >> 6;   // 0..2*BATCH-1
    int lane = threadIdx.x & 63;
    int g = lane >> 4;
    int l = lane & 15;        // uint2 slot: dims 4l..4l+3
    bool isU = w < BATCH;
    int b = isU ? w : w - BATCH;
    int idx = isU ? users[b] : items[b];
    int n = isU ? idx : N_USERS + idx;
    uint ri = rowinfo[n];
    int s = (int)(ri & 0x3FFFFFu);
    int e = s + (int)(ri >> 22);
    v2f a0 = {0.f, 0.f}, a1 = {0.f, 0.f};
    for (int j0 = s + g; j0 < e; j0 += 16) {
        int2 ev[4];
        float vv[4];
        uint2 rr[4];
#pragma unroll
        for (int u = 0; u < 4; ++u) {
            int j = j0 + 4 * u;
            bool p = (u == 0) || (j < e);
            ev[u] = epair[p ? j : j0];
            vv[u] = p ? __int_as_float(ev[u].y) : 0.f;
        }
#pragma unroll
        for (int u = 0; u < 4; ++u)
            rr[u] = ((const uint2*)(x2 + (size_t)ev[u].x * 32))[l];
#pragma unroll
        for (int u = 0; u < 4; ++u) {
            a0 += vv[u] * unpack_bf16x2(rr[u].x);
            a1 += vv[u] * unpack_bf16x2(rr[u].y);
        }
    }
#pragma unroll
    for (int off = 16; off < 64; off <<= 1) {
        a0.x += __shfl_xor(a0.x, off, 64);
        a0.y += __shfl_xor(a0.y, off, 64);
        a1.x += __shfl_xor(a1.x, off, 64);
        a1.y += __shfl_xor(a1.y, off, 64);
    }
    if (g == 0) {
        const float* t0row = isU ? (emb_user + (size_t)idx * DIM)
                                 : (emb_item + (size_t)idx * DIM);
        float4 x0 = ((const float4*)t0row)[l];
        uint2 w1 = ((const uint2*)(x1 + (size_t)n * 32))[l];
        uint2 w2 = ((const uint2*)(x2 + (size_t)n * 32))[l];
        v2f b10 = unpack_bf16x2(w1.x), b11 = unpack_bf16x2(w1.y);
        v2f b20 = unpack_bf16x2(w2.x), b21 = unpack_bf16x2(w2.y);
        float4 r;
        r.x = x0.x + b10.x + b20.x + a0.x;
        r.y = x0.y + b10.y + b20.y + a0.y;
        r.z = x0.z + b11.x + b21.x + a1.x;
        r.w = x0.w + b11.y + b21.y + a1.y;
        rows[(size_t)w * 16 + l] = r;
    }
}

// gamma[b] = dot(rows[b], rows[BATCH+b]) / 16
__global__ __launch_bounds__(256) void dot_kernel(const float* __restrict__ rows,
                                                  float* __restrict__ out) {
    int t = blockIdx.x * 256 + threadIdx.x;
    int b = t >> 6;
    int lane = t & 63;
    float p = rows[(size_t)b * DIM + lane] * rows[(size_t)(BATCH + b) * DIM + lane];
#pragma unroll
    for (int o = 32; o > 0; o >>= 1) p += __shfl_down(p, o, 64);
    if (lane == 0) out[b] = p * (1.0f / 16.0f);
}

extern "C" void kernel_launch(void* const* d_in, const int* in_sizes, int n_in,
                              void* d_out, int out_size, void* d_ws, size_t ws_size,
                              hipStream_t stream) {
    const float* emb_user = (const float*)d_in[0];
    const float* emb_item = (const float*)d_in[1];
    const float* vals     = (const float*)d_in[2];
    const int*   src      = (const int*)d_in[3];
    const int*   dst      = (const int*)d_in[4];
    const int*   users    = (const int*)d_in[5];
    const int*   items    = (const int*)d_in[6];
    float* out = (float*)d_out;

    char* ws = (char*)d_ws;
    size_t off = 0;
    auto walloc = [&](size_t bytes) -> void* {
        void* p = ws + off;
        off += (bytes + 255) & ~(size_t)255;
        return p;
    };
    const size_t ROWB = (size_t)N_NODES * DIM * 2;                  // 19.2 MB
    uint* t0          = (uint*)walloc(ROWB);                        // bf16 x0
    uint* x1          = (uint*)walloc(ROWB);
    uint* x2          = (uint*)walloc(ROWB);
    int2* coarse      = (int2*)walloc((size_t)KB * ECAP * 8);       // 21.0 MB
    int*  gcur        = (int*) walloc((size_t)KB * 4);
    uint* rowinfo     = (uint*)walloc((size_t)N_NODES * 4);
    float4* rows      = (float4*)walloc((size_t)2 * BATCH * DIM * 4); // 2 MB

    hipMemsetAsync(gcur, 0, (size_t)KB * 4, stream);

    // Build: single-pass partition (+ fused conv), then in-place fine sort
    part_kernel<<<CHUNKS + CONVB, 1024, 0, stream>>>(
        src, dst, vals, gcur, coarse, emb_user, emb_item, (uint2*)t0);
    p4f_fine<<<KB, 1024, 0, stream>>>(coarse, gcur, rowinfo);

    // Layers 1,2 full; layer 3 batch-only + dot
    spmm_kernel<<<N_NODES / 4, 256, 0, stream>>>(rowinfo, coarse, t0, x1);
    spmm_kernel<<<N_NODES / 4, 256, 0, stream>>>(rowinfo, coarse, x1, x2);
    batch_row_kernel<<<(2 * BATCH) / 4, 256, 0, stream>>>(
        users, items, emb_user, emb_item, x1, x2, rowinfo, coarse, rows);
    dot_kernel<<<(BATCH * 64) / 256, 256, 0, stream>>>((const float*)rows, out);
}

// Round 2
// 259.896 us; speedup vs baseline: 1.0932x; 1.0335x over previous
//
#include <hip/hip_runtime.h>

// LightGCN propagation: 3x SpMM over fixed COO graph + batched dot epilogue.
// R15: spmm restructured 1-node/wave -> 8-nodes/wave. R14 profile showed
// spmm VALU-issue-bound (VALUBusy 64%, HBM 35%): ~295 wave-instrs per
// 16-edge node, dominated by per-wave fixed cost (3-level x 8-component
// shfl_xor reduce = 24 DS + 24 VALU on a serial chain). Now each OCTET
// (8 lanes x uint4 = full 128B row) owns one node and serially
// accumulates its edges -> zero cross-lane reduce, direct pack+store,
// wave stores 8 consecutive rows = 1KB contiguous. Wave count 150K ->
// 18750. Cost: trip = max(deg over 8 nodes) ~ 22 vs mean 16 (Poisson),
// acceptable. part_kernel 256x1024 with register-cached dst (R14).
// Fine sort in place per super-bucket (80KB LDS, 1024thr). Layer 3
// batch-only (R10). bf16 rows (R5): compulsory fabric 8 XCD x 19.2MB/layer.

#define N_USERS 50000
#define N_ITEMS 100000
#define N_NODES 150000
#define N_EDGES 2400000
#define DIM 64
#define BATCH 4096

#define CHUNKS 256
#define CHUNK_EDGES 9375   // 256*9375 = 2400000 exact
#define PPT 10             // ceil(9375/1024) edges per thread per pass
#define KB 256             // super-buckets
#define NPB 586            // nodes per bucket; 256*586 = 150016 >= N_NODES
#define ECAP 10240         // bucket capacity: mean 9375, sigma 97 -> +8.9 sigma
#define CONVB 2344         // ceil(2400000 float4 / 1024)

typedef unsigned int uint;
typedef float v2f __attribute__((ext_vector_type(2)));

__device__ __forceinline__ uint pack_bf16(float a, float b) {
    uint ua = __float_as_uint(a), ub = __float_as_uint(b);
    ua = (ua + 0x7FFFu + ((ua >> 16) & 1u)) >> 16;   // RTNE
    ub = (ub + 0x7FFFu + ((ub >> 16) & 1u)) >> 16;
    return ua | (ub << 16);
}

__device__ __forceinline__ v2f unpack_bf16x2(uint w) {
    v2f r;
    r.x = __uint_as_float(w << 16);
    r.y = __uint_as_float(w & 0xFFFF0000u);
    return r;
}

// PART: blocks [0,CHUNKS): hist pass over dst (LDS, 2KB) -> one global
// atomicAdd per bucket reserves a fat run -> scatter pass uses
// register-cached dst + src/vals. Blocks [CHUNKS,..): fp32 -> bf16 concat t0.
__global__ __launch_bounds__(1024) void part_kernel(
        const int* __restrict__ src, const int* __restrict__ dstA,
        const float* __restrict__ vals, int* __restrict__ gcur,
        int2* __restrict__ coarse,
        const float* __restrict__ emb_user, const float* __restrict__ emb_item,
        uint2* __restrict__ t0) {
    int t = threadIdx.x;
    if (blockIdx.x >= CHUNKS) {
        int i = (blockIdx.x - CHUNKS) * 1024 + t;  // float4 index, 2.4M total
        if (i < N_NODES * DIM / 4) {
            const int userN4 = N_USERS * DIM / 4; // 800000
            float4 v;
            if (i < userN4) v = ((const float4*)emb_user)[i];
            else            v = ((const float4*)emb_item)[i - userN4];
            t0[i] = make_uint2(pack_bf16(v.x, v.y), pack_bf16(v.z, v.w));
        }
        return;
    }
    __shared__ int h[KB];
    __shared__ int cur[KB];
    int c = blockIdx.x;
    if (t < KB) h[t] = 0;
    __syncthreads();
    int base = c * CHUNK_EDGES;
    int d_c[PPT];
#pragma unroll
    for (int u = 0; u < PPT; ++u) {
        int i = t + u * 1024;
        d_c[u] = 0;
        if (i < CHUNK_EDGES) {
            int d = dstA[base + i];
            d_c[u] = d;
            atomicAdd(&h[(int)((unsigned)d / NPB)], 1);  // magic-mul div
        }
    }
    __syncthreads();
    if (t < KB) cur[t] = atomicAdd(&gcur[t], h[t]);      // reserve fat run
    __syncthreads();
#pragma unroll
    for (int u = 0; u < PPT; ++u) {
        int i = t + u * 1024;
        if (i < CHUNK_EDGES) {
            int e = base + i;
            int d = d_c[u];                              // from registers
            int b = (int)((unsigned)d / NPB);
            int dl = d - b * NPB;
            int p = atomicAdd(&cur[b], 1);
            if (p < ECAP)
                coarse[b * ECAP + p] = make_int2(src[e] | (dl << 18),
                                                 __float_as_int(vals[e]));
        }
    }
}

// P4F: per-super-bucket fine sort IN PLACE. Edges -> LDS (one read),
// histogram over 586 node counters, wave-shuffle scan, rowinfo emit,
// sorted scatter back into the same region.
__global__ __launch_bounds__(1024) void p4f_fine(int2* __restrict__ coarse,
                                                 const int* __restrict__ gcur,
                                                 uint* __restrict__ rowinfo) {
    __shared__ int2 eds[ECAP];        // 81920 B
    __shared__ int cnt[640];
    __shared__ int rs_[640];
    __shared__ int cur_[640];
    __shared__ int wsum[16];
    int k = blockIdx.x, t = threadIdx.x;
    int rbase = k * ECAP;
    int ne = min(gcur[k], ECAP);
    for (int i = t; i < ne; i += 1024) eds[i] = coarse[rbase + i];
    if (t < 640) cnt[t] = 0;
    __syncthreads();
    for (int i = t; i < ne; i += 1024)
        atomicAdd(&cnt[eds[i].x >> 18], 1);
    __syncthreads();
    int wid = t >> 6, lane = t & 63;
    if (t < 640) {                    // waves 0..9 (640 = 10*64)
        int v = cnt[t];
        int incl = v;
#pragma unroll
        for (int o = 1; o < 64; o <<= 1) {
            int add = __shfl_up(incl, o, 64);
            if (lane >= o) incl += add;
        }
        rs_[t] = incl - v;
        if (lane == 63) wsum[wid] = incl;
    }
    __syncthreads();
    if (t < 64) {
        int vv = (lane < 10) ? wsum[lane] : 0;
        int inc2 = vv;
#pragma unroll
        for (int o = 1; o < 16; o <<= 1) {
            int add = __shfl_up(inc2, o, 64);
            if (lane >= o) inc2 += add;
        }
        if (lane < 10) wsum[lane] = inc2 - vv;
    }
    __syncthreads();
    if (t < 640) rs_[t] += wsum[wid];
    __syncthreads();
    int nodes0 = k * NPB;
    int nb = min(NPB, N_NODES - nodes0);
    if (t < nb)
        rowinfo[nodes0 + t] = (uint)(rbase + rs_[t]) | ((uint)cnt[t] << 22);
    if (t < 640) cur_[t] = rs_[t];
    __syncthreads();
    for (int i = t; i < ne; i += 1024) {
        int2 ev = eds[i];
        int dl = ev.x >> 18;
        int p = atomicAdd(&cur_[dl], 1);
        coarse[rbase + p] = make_int2(ev.x & 0x3FFFF, ev.y);   // strip dl
    }
}

// SpMM over bf16 rows (128B/row). R15 form: 8 nodes per wave, one octet
// (8 lanes x uint4 = full row) per node; serial edge accumulation, 2x
// unrolled; NO cross-lane reduce; wave stores 1KB contiguous (8 rows).
__global__ __launch_bounds__(256) void spmm_kernel(
        const uint* __restrict__ rowinfo, const int2* __restrict__ epair,
        const uint* __restrict__ xin, uint* __restrict__ xout) {
    int wave = (blockIdx.x * 256 + threadIdx.x) >> 6;
    int lane = threadIdx.x & 63;
    int g = lane >> 3;                // octet id = node slot 0..7
    int l = lane & 7;                 // uint4 slot within row
    int n = wave * 8 + g;
    bool live = n < N_NODES;
    uint ri = live ? rowinfo[n] : 0u;
    int s = (int)(ri & 0x3FFFFFu);
    int e = live ? s + (int)(ri >> 22) : s;
    v2f a0 = {0.f, 0.f}, a1 = {0.f, 0.f}, a2 = {0.f, 0.f}, a3 = {0.f, 0.f};
    for (int j = s; j < e; j += 2) {
        int j1 = j + 1;
        bool p1 = j1 < e;
        int2 ev0 = epair[j];
        int2 ev1 = epair[p1 ? j1 : j];
        float v0 = __int_as_float(ev0.y);
        float v1 = p1 ? __int_as_float(ev1.y) : 0.f;
        uint4 r0 = ((const uint4*)(xin + (size_t)ev0.x * 32))[l];
        uint4 r1 = ((const uint4*)(xin + (size_t)ev1.x * 32))[l];
        a0 += v0 * unpack_bf16x2(r0.x);
        a1 += v0 * unpack_bf16x2(r0.y);
        a2 += v0 * unpack_bf16x2(r0.z);
        a3 += v0 * unpack_bf16x2(r0.w);
        a0 += v1 * unpack_bf16x2(r1.x);
        a1 += v1 * unpack_bf16x2(r1.y);
        a2 += v1 * unpack_bf16x2(r1.z);
        a3 += v1 * unpack_bf16x2(r1.w);
    }
    if (live) {
        uint4 o;
        o.x = pack_bf16(a0.x, a0.y);
        o.y = pack_bf16(a1.x, a1.y);
        o.z = pack_bf16(a2.x, a2.y);
        o.w = pack_bf16(a3.x, a3.y);
        ((uint4*)(xout + (size_t)n * 32))[l] = o;   // wave: 8 rows = 1KB contig
    }
}

// Layer-3 restricted to batch rows: one wave per batch node (2*BATCH waves).
// x3[n] = sum val*x2[src]; add x0 (fp32) + x1 + x2 (bf16); store fp32 row.
__global__ __launch_bounds__(256) void batch_row_kernel(
        const int* __restrict__ users, const int* __restrict__ items,
        const float* __restrict__ emb_user, const float* __restrict__ emb_item,
        const uint* __restrict__ x1, const uint* __restrict__ x2,
        const uint* __restrict__ rowinfo, const int2* __restrict__ epair,
        float4* __restrict__ rows) {
    int w = (blockIdx.x * 256 + threadIdx.x) >> 6;   // 0..2*BATCH-1
    int lane = threadIdx.x & 63;
    int g = lane >> 4;
    int l = lane & 15;        // uint2 slot: dims 4l..4l+3
    bool isU = w < BATCH;
    int b = isU ? w : w - BATCH;
    int idx = isU ? users[b] : items[b];
    int n = isU ? idx : N_USERS + idx;
    uint ri = rowinfo[n];
    int s = (int)(ri & 0x3FFFFFu);
    int e = s + (int)(ri >> 22);
    v2f a0 = {0.f, 0.f}, a1 = {0.f, 0.f};
    for (int j0 = s + g; j0 < e; j0 += 16) {
        int2 ev[4];
        float vv[4];
        uint2 rr[4];
#pragma unroll
        for (int u = 0; u < 4; ++u) {
            int j = j0 + 4 * u;
            bool p = (u == 0) || (j < e);
            ev[u] = epair[p ? j : j0];
            vv[u] = p ? __int_as_float(ev[u].y) : 0.f;
        }
#pragma unroll
        for (int u = 0; u < 4; ++u)
            rr[u] = ((const uint2*)(x2 + (size_t)ev[u].x * 32))[l];
#pragma unroll
        for (int u = 0; u < 4; ++u) {
            a0 += vv[u] * unpack_bf16x2(rr[u].x);
            a1 += vv[u] * unpack_bf16x2(rr[u].y);
        }
    }
#pragma unroll
    for (int off = 16; off < 64; off <<= 1) {
        a0.x += __shfl_xor(a0.x, off, 64);
        a0.y += __shfl_xor(a0.y, off, 64);
        a1.x += __shfl_xor(a1.x, off, 64);
        a1.y += __shfl_xor(a1.y, off, 64);
    }
    if (g == 0) {
        const float* t0row = isU ? (emb_user + (size_t)idx * DIM)
                                 : (emb_item + (size_t)idx * DIM);
        float4 x0 = ((const float4*)t0row)[l];
        uint2 w1 = ((const uint2*)(x1 + (size_t)n * 32))[l];
        uint2 w2 = ((const uint2*)(x2 + (size_t)n * 32))[l];
        v2f b10 = unpack_bf16x2(w1.x), b11 = unpack_bf16x2(w1.y);
        v2f b20 = unpack_bf16x2(w2.x), b21 = unpack_bf16x2(w2.y);
        float4 r;
        r.x = x0.x + b10.x + b20.x + a0.x;
        r.y = x0.y + b10.y + b20.y + a0.y;
        r.z = x0.z + b11.x + b21.x + a1.x;
        r.w = x0.w + b11.y + b21.y + a1.y;
        rows[(size_t)w * 16 + l] = r;
    }
}

// gamma[b] = dot(rows[b], rows[BATCH+b]) / 16
__global__ __launch_bounds__(256) void dot_kernel(const float* __restrict__ rows,
                                                  float* __restrict__ out) {
    int t = blockIdx.x * 256 + threadIdx.x;
    int b = t >> 6;
    int lane = t & 63;
    float p = rows[(size_t)b * DIM + lane] * rows[(size_t)(BATCH + b) * DIM + lane];
#pragma unroll
    for (int o = 32; o > 0; o >>= 1) p += __shfl_down(p, o, 64);
    if (lane == 0) out[b] = p * (1.0f / 16.0f);
}

extern "C" void kernel_launch(void* const* d_in, const int* in_sizes, int n_in,
                              void* d_out, int out_size, void* d_ws, size_t ws_size,
                              hipStream_t stream) {
    const float* emb_user = (const float*)d_in[0];
    const float* emb_item = (const float*)d_in[1];
    const float* vals     = (const float*)d_in[2];
    const int*   src      = (const int*)d_in[3];
    const int*   dst      = (const int*)d_in[4];
    const int*   users    = (const int*)d_in[5];
    const int*   items    = (const int*)d_in[6];
    float* out = (float*)d_out;

    char* ws = (char*)d_ws;
    size_t off = 0;
    auto walloc = [&](size_t bytes) -> void* {
        void* p = ws + off;
        off += (bytes + 255) & ~(size_t)255;
        return p;
    };
    const size_t ROWB = (size_t)N_NODES * DIM * 2;                  // 19.2 MB
    uint* t0          = (uint*)walloc(ROWB);                        // bf16 x0
    uint* x1          = (uint*)walloc(ROWB);
    uint* x2          = (uint*)walloc(ROWB);
    int2* coarse      = (int2*)walloc((size_t)KB * ECAP * 8);       // 21.0 MB
    int*  gcur        = (int*) walloc((size_t)KB * 4);
    uint* rowinfo     = (uint*)walloc((size_t)N_NODES * 4);
    float4* rows      = (float4*)walloc((size_t)2 * BATCH * DIM * 4); // 2 MB

    hipMemsetAsync(gcur, 0, (size_t)KB * 4, stream);

    // Build: single-pass partition (+ fused conv), then in-place fine sort
    part_kernel<<<CHUNKS + CONVB, 1024, 0, stream>>>(
        src, dst, vals, gcur, coarse, emb_user, emb_item, (uint2*)t0);
    p4f_fine<<<KB, 1024, 0, stream>>>(coarse, gcur, rowinfo);

    // Layers 1,2 full; layer 3 batch-only + dot
    // 18750 node-waves (8 nodes/wave) -> 1.2M threads -> 4688 blocks (guarded)
    const int SPMM_BLOCKS = (N_NODES / 8 * 64 + 255) / 256;
    spmm_kernel<<<SPMM_BLOCKS, 256, 0, stream>>>(rowinfo, coarse, t0, x1);
    spmm_kernel<<<SPMM_BLOCKS, 256, 0, stream>>>(rowinfo, coarse, x1, x2);
    batch_row_kernel<<<(2 * BATCH) / 4, 256, 0, stream>>>(
        users, items, emb_user, emb_item, x1, x2, rowinfo, coarse, rows);
    dot_kernel<<<(BATCH * 64) / 256, 256, 0, stream>>>((const float*)rows, out);
}

// Round 3
// 256.080 us; speedup vs baseline: 1.1095x; 1.0149x over previous
//
#include <hip/hip_runtime.h>

// LightGCN propagation: 3x SpMM over fixed COO graph + batched dot epilogue.
// R16: spmm gather-MLP widened. R15 profile: VALUBusy 27%, HBM 40%,
// occupancy 64% -> latency-bound on the serial epair->row dependent
// chain (2 edges in flight). Now each octet cooperatively loads 8
// epair entries (one 64B coalesced access), __shfl-broadcasts src/val
// within the octet, and issues 8 INDEPENDENT row gathers before the
// FMA block -> 8 loads in flight per octet. Tail lanes clamp to edge
// e-1 (same cache line as an active lane -> no extra traffic, weight 0).
// 8-nodes/wave octet structure from R15 (no cross-lane reduce, 1KB
// contiguous store). part_kernel 256x1024, register-cached dst (R14).
// Fine sort in place per super-bucket (80KB LDS, 1024thr). Layer 3
// batch-only (R10). bf16 rows (R5): compulsory fabric 8 XCD x 19.2MB/layer.

#define N_USERS 50000
#define N_ITEMS 100000
#define N_NODES 150000
#define N_EDGES 2400000
#define DIM 64
#define BATCH 4096

#define CHUNKS 256
#define CHUNK_EDGES 9375   // 256*9375 = 2400000 exact
#define PPT 10             // ceil(9375/1024) edges per thread per pass
#define KB 256             // super-buckets
#define NPB 586            // nodes per bucket; 256*586 = 150016 >= N_NODES
#define ECAP 10240         // bucket capacity: mean 9375, sigma 97 -> +8.9 sigma
#define CONVB 2344         // ceil(2400000 float4 / 1024)

typedef unsigned int uint;
typedef float v2f __attribute__((ext_vector_type(2)));

__device__ __forceinline__ uint pack_bf16(float a, float b) {
    uint ua = __float_as_uint(a), ub = __float_as_uint(b);
    ua = (ua + 0x7FFFu + ((ua >> 16) & 1u)) >> 16;   // RTNE
    ub = (ub + 0x7FFFu + ((ub >> 16) & 1u)) >> 16;
    return ua | (ub << 16);
}

__device__ __forceinline__ v2f unpack_bf16x2(uint w) {
    v2f r;
    r.x = __uint_as_float(w << 16);
    r.y = __uint_as_float(w & 0xFFFF0000u);
    return r;
}

// PART: blocks [0,CHUNKS): hist pass over dst (LDS, 2KB) -> one global
// atomicAdd per bucket reserves a fat run -> scatter pass uses
// register-cached dst + src/vals. Blocks [CHUNKS,..): fp32 -> bf16 concat t0.
__global__ __launch_bounds__(1024) void part_kernel(
        const int* __restrict__ src, const int* __restrict__ dstA,
        const float* __restrict__ vals, int* __restrict__ gcur,
        int2* __restrict__ coarse,
        const float* __restrict__ emb_user, const float* __restrict__ emb_item,
        uint2* __restrict__ t0) {
    int t = threadIdx.x;
    if (blockIdx.x >= CHUNKS) {
        int i = (blockIdx.x - CHUNKS) * 1024 + t;  // float4 index, 2.4M total
        if (i < N_NODES * DIM / 4) {
            const int userN4 = N_USERS * DIM / 4; // 800000
            float4 v;
            if (i < userN4) v = ((const float4*)emb_user)[i];
            else            v = ((const float4*)emb_item)[i - userN4];
            t0[i] = make_uint2(pack_bf16(v.x, v.y), pack_bf16(v.z, v.w));
        }
        return;
    }
    __shared__ int h[KB];
    __shared__ int cur[KB];
    int c = blockIdx.x;
    if (t < KB) h[t] = 0;
    __syncthreads();
    int base = c * CHUNK_EDGES;
    int d_c[PPT];
#pragma unroll
    for (int u = 0; u < PPT; ++u) {
        int i = t + u * 1024;
        d_c[u] = 0;
        if (i < CHUNK_EDGES) {
            int d = dstA[base + i];
            d_c[u] = d;
            atomicAdd(&h[(int)((unsigned)d / NPB)], 1);  // magic-mul div
        }
    }
    __syncthreads();
    if (t < KB) cur[t] = atomicAdd(&gcur[t], h[t]);      // reserve fat run
    __syncthreads();
#pragma unroll
    for (int u = 0; u < PPT; ++u) {
        int i = t + u * 1024;
        if (i < CHUNK_EDGES) {
            int e = base + i;
            int d = d_c[u];                              // from registers
            int b = (int)((unsigned)d / NPB);
            int dl = d - b * NPB;
            int p = atomicAdd(&cur[b], 1);
            if (p < ECAP)
                coarse[b * ECAP + p] = make_int2(src[e] | (dl << 18),
                                                 __float_as_int(vals[e]));
        }
    }
}

// P4F: per-super-bucket fine sort IN PLACE. Edges -> LDS (one read),
// histogram over 586 node counters, wave-shuffle scan, rowinfo emit,
// sorted scatter back into the same region.
__global__ __launch_bounds__(1024) void p4f_fine(int2* __restrict__ coarse,
                                                 const int* __restrict__ gcur,
                                                 uint* __restrict__ rowinfo) {
    __shared__ int2 eds[ECAP];        // 81920 B
    __shared__ int cnt[640];
    __shared__ int rs_[640];
    __shared__ int cur_[640];
    __shared__ int wsum[16];
    int k = blockIdx.x, t = threadIdx.x;
    int rbase = k * ECAP;
    int ne = min(gcur[k], ECAP);
    for (int i = t; i < ne; i += 1024) eds[i] = coarse[rbase + i];
    if (t < 640) cnt[t] = 0;
    __syncthreads();
    for (int i = t; i < ne; i += 1024)
        atomicAdd(&cnt[eds[i].x >> 18], 1);
    __syncthreads();
    int wid = t >> 6, lane = t & 63;
    if (t < 640) {                    // waves 0..9 (640 = 10*64)
        int v = cnt[t];
        int incl = v;
#pragma unroll
        for (int o = 1; o < 64; o <<= 1) {
            int add = __shfl_up(incl, o, 64);
            if (lane >= o) incl += add;
        }
        rs_[t] = incl - v;
        if (lane == 63) wsum[wid] = incl;
    }
    __syncthreads();
    if (t < 64) {
        int vv = (lane < 10) ? wsum[lane] : 0;
        int inc2 = vv;
#pragma unroll
        for (int o = 1; o < 16; o <<= 1) {
            int add = __shfl_up(inc2, o, 64);
            if (lane >= o) inc2 += add;
        }
        if (lane < 10) wsum[lane] = inc2 - vv;
    }
    __syncthreads();
    if (t < 640) rs_[t] += wsum[wid];
    __syncthreads();
    int nodes0 = k * NPB;
    int nb = min(NPB, N_NODES - nodes0);
    if (t < nb)
        rowinfo[nodes0 + t] = (uint)(rbase + rs_[t]) | ((uint)cnt[t] << 22);
    if (t < 640) cur_[t] = rs_[t];
    __syncthreads();
    for (int i = t; i < ne; i += 1024) {
        int2 ev = eds[i];
        int dl = ev.x >> 18;
        int p = atomicAdd(&cur_[dl], 1);
        coarse[rbase + p] = make_int2(ev.x & 0x3FFFF, ev.y);   // strip dl
    }
}

// SpMM over bf16 rows (128B/row). R16 form: 8 nodes per wave, one octet
// (8 lanes x uint4 = full row) per node. Per round: octet cooperatively
// loads 8 epair entries (64B coalesced), shfl-broadcasts src/val, issues
// 8 independent row gathers, then FMAs. No cross-lane reduce; wave
// stores 1KB contiguous (8 rows).
__global__ __launch_bounds__(256) void spmm_kernel(
        const uint* __restrict__ rowinfo, const int2* __restrict__ epair,
        const uint* __restrict__ xin, uint* __restrict__ xout) {
    int wave = (blockIdx.x * 256 + threadIdx.x) >> 6;
    int lane = threadIdx.x & 63;
    int g = lane >> 3;                // octet id = node slot 0..7
    int l = lane & 7;                 // uint4 slot within row
    int n = wave * 8 + g;
    bool live = n < N_NODES;
    uint ri = live ? rowinfo[n] : 0u;
    int s = (int)(ri & 0x3FFFFFu);
    int e = live ? s + (int)(ri >> 22) : s;   // empty/dead: e==s skips loop
    int gbase = g * 8;
    v2f a0 = {0.f, 0.f}, a1 = {0.f, 0.f}, a2 = {0.f, 0.f}, a3 = {0.f, 0.f};
    for (int jb = s; jb < e; jb += 8) {
        int jl = jb + l;
        // cooperative 64B epair fetch; tail clamps to e-1 (same line, w=0)
        int2 ev = epair[jl < e ? jl : (e - 1)];
        float vw = (jl < e) ? __int_as_float(ev.y) : 0.f;
        int sx = ev.x;
        int srcs[8];
        float ws[8];
#pragma unroll
        for (int u = 0; u < 8; ++u) {
            srcs[u] = __shfl(sx, gbase + u, 64);
            ws[u]   = __shfl(vw, gbase + u, 64);
        }
        uint4 r[8];
#pragma unroll
        for (int u = 0; u < 8; ++u)
            r[u] = ((const uint4*)(xin + (size_t)srcs[u] * 32))[l];
#pragma unroll
        for (int u = 0; u < 8; ++u) {
            a0 += ws[u] * unpack_bf16x2(r[u].x);
            a1 += ws[u] * unpack_bf16x2(r[u].y);
            a2 += ws[u] * unpack_bf16x2(r[u].z);
            a3 += ws[u] * unpack_bf16x2(r[u].w);
        }
    }
    if (live) {
        uint4 o;
        o.x = pack_bf16(a0.x, a0.y);
        o.y = pack_bf16(a1.x, a1.y);
        o.z = pack_bf16(a2.x, a2.y);
        o.w = pack_bf16(a3.x, a3.y);
        ((uint4*)(xout + (size_t)n * 32))[l] = o;   // wave: 8 rows = 1KB contig
    }
}

// Layer-3 restricted to batch rows: one wave per batch node (2*BATCH waves).
// x3[n] = sum val*x2[src]; add x0 (fp32) + x1 + x2 (bf16); store fp32 row.
__global__ __launch_bounds__(256) void batch_row_kernel(
        const int* __restrict__ users, const int* __restrict__ items,
        const float* __restrict__ emb_user, const float* __restrict__ emb_item,
        const uint* __restrict__ x1, const uint* __restrict__ x2,
        const uint* __restrict__ rowinfo, const int2* __restrict__ epair,
        float4* __restrict__ rows) {
    int w = (blockIdx.x * 256 + threadIdx.x) >> 6;   // 0..2*BATCH-1
    int lane = threadIdx.x & 63;
    int g = lane >> 4;
    int l = lane & 15;        // uint2 slot: dims 4l..4l+3
    bool isU = w < BATCH;
    int b = isU ? w : w - BATCH;
    int idx = isU ? users[b] : items[b];
    int n = isU ? idx : N_USERS + idx;
    uint ri = rowinfo[n];
    int s = (int)(ri & 0x3FFFFFu);
    int e = s + (int)(ri >> 22);
    v2f a0 = {0.f, 0.f}, a1 = {0.f, 0.f};
    for (int j0 = s + g; j0 < e; j0 += 16) {
        int2 ev[4];
        float vv[4];
        uint2 rr[4];
#pragma unroll
        for (int u = 0; u < 4; ++u) {
            int j = j0 + 4 * u;
            bool p = (u == 0) || (j < e);
            ev[u] = epair[p ? j : j0];
            vv[u] = p ? __int_as_float(ev[u].y) : 0.f;
        }
#pragma unroll
        for (int u = 0; u < 4; ++u)
            rr[u] = ((const uint2*)(x2 + (size_t)ev[u].x * 32))[l];
#pragma unroll
        for (int u = 0; u < 4; ++u) {
            a0 += vv[u] * unpack_bf16x2(rr[u].x);
            a1 += vv[u] * unpack_bf16x2(rr[u].y);
        }
    }
#pragma unroll
    for (int off = 16; off < 64; off <<= 1) {
        a0.x += __shfl_xor(a0.x, off, 64);
        a0.y += __shfl_xor(a0.y, off, 64);
        a1.x += __shfl_xor(a1.x, off, 64);
        a1.y += __shfl_xor(a1.y, off, 64);
    }
    if (g == 0) {
        const float* t0row = isU ? (emb_user + (size_t)idx * DIM)
                                 : (emb_item + (size_t)idx * DIM);
        float4 x0 = ((const float4*)t0row)[l];
        uint2 w1 = ((const uint2*)(x1 + (size_t)n * 32))[l];
        uint2 w2 = ((const uint2*)(x2 + (size_t)n * 32))[l];
        v2f b10 = unpack_bf16x2(w1.x), b11 = unpack_bf16x2(w1.y);
        v2f b20 = unpack_bf16x2(w2.x), b21 = unpack_bf16x2(w2.y);
        float4 r;
        r.x = x0.x + b10.x + b20.x + a0.x;
        r.y = x0.y + b10.y + b20.y + a0.y;
        r.z = x0.z + b11.x + b21.x + a1.x;
        r.w = x0.w + b11.y + b21.y + a1.y;
        rows[(size_t)w * 16 + l] = r;
    }
}

// gamma[b] = dot(rows[b], rows[BATCH+b]) / 16
__global__ __launch_bounds__(256) void dot_kernel(const float* __restrict__ rows,
                                                  float* __restrict__ out) {
    int t = blockIdx.x * 256 + threadIdx.x;
    int b = t >> 6;
    int lane = t & 63;
    float p = rows[(size_t)b * DIM + lane] * rows[(size_t)(BATCH + b) * DIM + lane];
#pragma unroll
    for (int o = 32; o > 0; o >>= 1) p += __shfl_down(p, o, 64);
    if (lane == 0) out[b] = p * (1.0f / 16.0f);
}

extern "C" void kernel_launch(void* const* d_in, const int* in_sizes, int n_in,
                              void* d_out, int out_size, void* d_ws, size_t ws_size,
                              hipStream_t stream) {
    const float* emb_user = (const float*)d_in[0];
    const float* emb_item = (const float*)d_in[1];
    const float* vals     = (const float*)d_in[2];
    const int*   src      = (const int*)d_in[3];
    const int*   dst      = (const int*)d_in[4];
    const int*   users    = (const int*)d_in[5];
    const int*   items    = (const int*)d_in[6];
    float* out = (float*)d_out;

    char* ws = (char*)d_ws;
    size_t off = 0;
    auto walloc = [&](size_t bytes) -> void* {
        void* p = ws + off;
        off += (bytes + 255) & ~(size_t)255;
        return p;
    };
    const size_t ROWB = (size_t)N_NODES * DIM * 2;                  // 19.2 MB
    uint* t0          = (uint*)walloc(ROWB);                        // bf16 x0
    uint* x1          = (uint*)walloc(ROWB);
    uint* x2          = (uint*)walloc(ROWB);
    int2* coarse      = (int2*)walloc((size_t)KB * ECAP * 8);       // 21.0 MB
    int*  gcur        = (int*) walloc((size_t)KB * 4);
    uint* rowinfo     = (uint*)walloc((size_t)N_NODES * 4);
    float4* rows      = (float4*)walloc((size_t)2 * BATCH * DIM * 4); // 2 MB

    hipMemsetAsync(gcur, 0, (size_t)KB * 4, stream);

    // Build: single-pass partition (+ fused conv), then in-place fine sort
    part_kernel<<<CHUNKS + CONVB, 1024, 0, stream>>>(
        src, dst, vals, gcur, coarse, emb_user, emb_item, (uint2*)t0);
    p4f_fine<<<KB, 1024, 0, stream>>>(coarse, gcur, rowinfo);

    // Layers 1,2 full; layer 3 batch-only + dot
    // 18750 node-waves (8 nodes/wave) -> 1.2M threads -> 4688 blocks (guarded)
    const int SPMM_BLOCKS = (N_NODES / 8 * 64 + 255) / 256;
    spmm_kernel<<<SPMM_BLOCKS, 256, 0, stream>>>(rowinfo, coarse, t0, x1);
    spmm_kernel<<<SPMM_BLOCKS, 256, 0, stream>>>(rowinfo, coarse, x1, x2);
    batch_row_kernel<<<(2 * BATCH) / 4, 256, 0, stream>>>(
        users, items, emb_user, emb_item, x1, x2, rowinfo, coarse, rows);
    dot_kernel<<<(BATCH * 64) / 256, 256, 0, stream>>>((const float*)rows, out);
}

// Round 4
// 251.837 us; speedup vs baseline: 1.1282x; 1.0168x over previous
//
#include <hip/hip_runtime.h>

// LightGCN propagation: 3x SpMM over fixed COO graph + batched dot epilogue.
// R17: part_kernel scatter made atomic-free. R16 profile: part 50.5us for
// 81MB (VALU 3.9%, occ 59%) = pure dependent-latency on pass-2's per-edge
// LDS atomicAdd -> dependent store chain (10 serial iters). Now pass 1's
// histogram atomic is the RETURNING form: pl = atomicAdd(&h[b],1) gives
// each edge its rank within (block,bucket); the 10 per-thread atomics are
// independent -> pipeline. Pass 2 = independent src/vals loads + cur[b]
// LDS read + store at cur[b]+pl: zero atomics, no chain.
// spmm (R16): 8 nodes/wave octets, cooperative 64B epair fetch, 8-deep
// row-gather MLP; near the ~3.5TB/s random-128B-gather fabric ceiling
// (FETCH = 8 XCD x 18MB compulsory). part 256x1024 (R14). Fine sort in
// place per super-bucket (80KB LDS, 1024thr). Layer 3 batch-only (R10).
// bf16 rows (R5).

#define N_USERS 50000
#define N_ITEMS 100000
#define N_NODES 150000
#define N_EDGES 2400000
#define DIM 64
#define BATCH 4096

#define CHUNKS 256
#define CHUNK_EDGES 9375   // 256*9375 = 2400000 exact
#define PPT 10             // ceil(9375/1024) edges per thread per pass
#define KB 256             // super-buckets
#define NPB 586            // nodes per bucket; 256*586 = 150016 >= N_NODES
#define ECAP 10240         // bucket capacity: mean 9375, sigma 97 -> +8.9 sigma
#define CONVB 2344         // ceil(2400000 float4 / 1024)

typedef unsigned int uint;
typedef float v2f __attribute__((ext_vector_type(2)));

__device__ __forceinline__ uint pack_bf16(float a, float b) {
    uint ua = __float_as_uint(a), ub = __float_as_uint(b);
    ua = (ua + 0x7FFFu + ((ua >> 16) & 1u)) >> 16;   // RTNE
    ub = (ub + 0x7FFFu + ((ub >> 16) & 1u)) >> 16;
    return ua | (ub << 16);
}

__device__ __forceinline__ v2f unpack_bf16x2(uint w) {
    v2f r;
    r.x = __uint_as_float(w << 16);
    r.y = __uint_as_float(w & 0xFFFF0000u);
    return r;
}

// PART: blocks [0,CHUNKS): returning-hist pass over dst (rank within
// block-bucket) -> one global atomicAdd per bucket reserves a fat run ->
// atomic-free scatter at cur[b]+rank. Blocks [CHUNKS,..): fp32 -> bf16
// concat t0.
__global__ __launch_bounds__(1024) void part_kernel(
        const int* __restrict__ src, const int* __restrict__ dstA,
        const float* __restrict__ vals, int* __restrict__ gcur,
        int2* __restrict__ coarse,
        const float* __restrict__ emb_user, const float* __restrict__ emb_item,
        uint2* __restrict__ t0) {
    int t = threadIdx.x;
    if (blockIdx.x >= CHUNKS) {
        int i = (blockIdx.x - CHUNKS) * 1024 + t;  // float4 index, 2.4M total
        if (i < N_NODES * DIM / 4) {
            const int userN4 = N_USERS * DIM / 4; // 800000
            float4 v;
            if (i < userN4) v = ((const float4*)emb_user)[i];
            else            v = ((const float4*)emb_item)[i - userN4];
            t0[i] = make_uint2(pack_bf16(v.x, v.y), pack_bf16(v.z, v.w));
        }
        return;
    }
    __shared__ int h[KB];
    __shared__ int cur[KB];
    int c = blockIdx.x;
    if (t < KB) h[t] = 0;
    __syncthreads();
    int base = c * CHUNK_EDGES;
    int d_c[PPT];
    int pl_c[PPT];
#pragma unroll
    for (int u = 0; u < PPT; ++u) {
        int i = t + u * 1024;
        d_c[u] = 0;
        pl_c[u] = 0;
        if (i < CHUNK_EDGES) {
            int d = dstA[base + i];
            d_c[u] = d;
            // returning atomic: rank of this edge within (block,bucket).
            // 10 independent atomics per thread -> pipelined.
            pl_c[u] = atomicAdd(&h[(int)((unsigned)d / NPB)], 1);
        }
    }
    __syncthreads();
    if (t < KB) cur[t] = atomicAdd(&gcur[t], h[t]);      // reserve fat run
    __syncthreads();
#pragma unroll
    for (int u = 0; u < PPT; ++u) {
        int i = t + u * 1024;
        if (i < CHUNK_EDGES) {
            int e = base + i;
            int d = d_c[u];                              // from registers
            int b = (int)((unsigned)d / NPB);
            int dl = d - b * NPB;
            int p = cur[b] + pl_c[u];                    // atomic-free
            if (p < ECAP)
                coarse[b * ECAP + p] = make_int2(src[e] | (dl << 18),
                                                 __float_as_int(vals[e]));
        }
    }
}

// P4F: per-super-bucket fine sort IN PLACE. Edges -> LDS (one read),
// histogram over 586 node counters, wave-shuffle scan, rowinfo emit,
// sorted scatter back into the same region.
__global__ __launch_bounds__(1024) void p4f_fine(int2* __restrict__ coarse,
                                                 const int* __restrict__ gcur,
                                                 uint* __restrict__ rowinfo) {
    __shared__ int2 eds[ECAP];        // 81920 B
    __shared__ int cnt[640];
    __shared__ int rs_[640];
    __shared__ int cur_[640];
    __shared__ int wsum[16];
    int k = blockIdx.x, t = threadIdx.x;
    int rbase = k * ECAP;
    int ne = min(gcur[k], ECAP);
    for (int i = t; i < ne; i += 1024) eds[i] = coarse[rbase + i];
    if (t < 640) cnt[t] = 0;
    __syncthreads();
    for (int i = t; i < ne; i += 1024)
        atomicAdd(&cnt[eds[i].x >> 18], 1);
    __syncthreads();
    int wid = t >> 6, lane = t & 63;
    if (t < 640) {                    // waves 0..9 (640 = 10*64)
        int v = cnt[t];
        int incl = v;
#pragma unroll
        for (int o = 1; o < 64; o <<= 1) {
            int add = __shfl_up(incl, o, 64);
            if (lane >= o) incl += add;
        }
        rs_[t] = incl - v;
        if (lane == 63) wsum[wid] = incl;
    }
    __syncthreads();
    if (t < 64) {
        int vv = (lane < 10) ? wsum[lane] : 0;
        int inc2 = vv;
#pragma unroll
        for (int o = 1; o < 16; o <<= 1) {
            int add = __shfl_up(inc2, o, 64);
            if (lane >= o) inc2 += add;
        }
        if (lane < 10) wsum[lane] = inc2 - vv;
    }
    __syncthreads();
    if (t < 640) rs_[t] += wsum[wid];
    __syncthreads();
    int nodes0 = k * NPB;
    int nb = min(NPB, N_NODES - nodes0);
    if (t < nb)
        rowinfo[nodes0 + t] = (uint)(rbase + rs_[t]) | ((uint)cnt[t] << 22);
    if (t < 640) cur_[t] = rs_[t];
    __syncthreads();
    for (int i = t; i < ne; i += 1024) {
        int2 ev = eds[i];
        int dl = ev.x >> 18;
        int p = atomicAdd(&cur_[dl], 1);
        coarse[rbase + p] = make_int2(ev.x & 0x3FFFF, ev.y);   // strip dl
    }
}

// SpMM over bf16 rows (128B/row). R16 form: 8 nodes per wave, one octet
// (8 lanes x uint4 = full row) per node. Per round: octet cooperatively
// loads 8 epair entries (64B coalesced), shfl-broadcasts src/val, issues
// 8 independent row gathers, then FMAs. No cross-lane reduce; wave
// stores 1KB contiguous (8 rows).
__global__ __launch_bounds__(256) void spmm_kernel(
        const uint* __restrict__ rowinfo, const int2* __restrict__ epair,
        const uint* __restrict__ xin, uint* __restrict__ xout) {
    int wave = (blockIdx.x * 256 + threadIdx.x) >> 6;
    int lane = threadIdx.x & 63;
    int g = lane >> 3;                // octet id = node slot 0..7
    int l = lane & 7;                 // uint4 slot within row
    int n = wave * 8 + g;
    bool live = n < N_NODES;
    uint ri = live ? rowinfo[n] : 0u;
    int s = (int)(ri & 0x3FFFFFu);
    int e = live ? s + (int)(ri >> 22) : s;   // empty/dead: e==s skips loop
    int gbase = g * 8;
    v2f a0 = {0.f, 0.f}, a1 = {0.f, 0.f}, a2 = {0.f, 0.f}, a3 = {0.f, 0.f};
    for (int jb = s; jb < e; jb += 8) {
        int jl = jb + l;
        // cooperative 64B epair fetch; tail clamps to e-1 (same line, w=0)
        int2 ev = epair[jl < e ? jl : (e - 1)];
        float vw = (jl < e) ? __int_as_float(ev.y) : 0.f;
        int sx = ev.x;
        int srcs[8];
        float ws[8];
#pragma unroll
        for (int u = 0; u < 8; ++u) {
            srcs[u] = __shfl(sx, gbase + u, 64);
            ws[u]   = __shfl(vw, gbase + u, 64);
        }
        uint4 r[8];
#pragma unroll
        for (int u = 0; u < 8; ++u)
            r[u] = ((const uint4*)(xin + (size_t)srcs[u] * 32))[l];
#pragma unroll
        for (int u = 0; u < 8; ++u) {
            a0 += ws[u] * unpack_bf16x2(r[u].x);
            a1 += ws[u] * unpack_bf16x2(r[u].y);
            a2 += ws[u] * unpack_bf16x2(r[u].z);
            a3 += ws[u] * unpack_bf16x2(r[u].w);
        }
    }
    if (live) {
        uint4 o;
        o.x = pack_bf16(a0.x, a0.y);
        o.y = pack_bf16(a1.x, a1.y);
        o.z = pack_bf16(a2.x, a2.y);
        o.w = pack_bf16(a3.x, a3.y);
        ((uint4*)(xout + (size_t)n * 32))[l] = o;   // wave: 8 rows = 1KB contig
    }
}

// Layer-3 restricted to batch rows: one wave per batch node (2*BATCH waves).
// x3[n] = sum val*x2[src]; add x0 (fp32) + x1 + x2 (bf16); store fp32 row.
__global__ __launch_bounds__(256) void batch_row_kernel(
        const int* __restrict__ users, const int* __restrict__ items,
        const float* __restrict__ emb_user, const float* __restrict__ emb_item,
        const uint* __restrict__ x1, const uint* __restrict__ x2,
        const uint* __restrict__ rowinfo, const int2* __restrict__ epair,
        float4* __restrict__ rows) {
    int w = (blockIdx.x * 256 + threadIdx.x) >> 6;   // 0..2*BATCH-1
    int lane = threadIdx.x & 63;
    int g = lane >> 4;
    int l = lane & 15;        // uint2 slot: dims 4l..4l+3
    bool isU = w < BATCH;
    int b = isU ? w : w - BATCH;
    int idx = isU ? users[b] : items[b];
    int n = isU ? idx : N_USERS + idx;
    uint ri = rowinfo[n];
    int s = (int)(ri & 0x3FFFFFu);
    int e = s + (int)(ri >> 22);
    v2f a0 = {0.f, 0.f}, a1 = {0.f, 0.f};
    for (int j0 = s + g; j0 < e; j0 += 16) {
        int2 ev[4];
        float vv[4];
        uint2 rr[4];
#pragma unroll
        for (int u = 0; u < 4; ++u) {
            int j = j0 + 4 * u;
            bool p = (u == 0) || (j < e);
            ev[u] = epair[p ? j : j0];
            vv[u] = p ? __int_as_float(ev[u].y) : 0.f;
        }
#pragma unroll
        for (int u = 0; u < 4; ++u)
            rr[u] = ((const uint2*)(x2 + (size_t)ev[u].x * 32))[l];
#pragma unroll
        for (int u = 0; u < 4; ++u) {
            a0 += vv[u] * unpack_bf16x2(rr[u].x);
            a1 += vv[u] * unpack_bf16x2(rr[u].y);
        }
    }
#pragma unroll
    for (int off = 16; off < 64; off <<= 1) {
        a0.x += __shfl_xor(a0.x, off, 64);
        a0.y += __shfl_xor(a0.y, off, 64);
        a1.x += __shfl_xor(a1.x, off, 64);
        a1.y += __shfl_xor(a1.y, off, 64);
    }
    if (g == 0) {
        const float* t0row = isU ? (emb_user + (size_t)idx * DIM)
                                 : (emb_item + (size_t)idx * DIM);
        float4 x0 = ((const float4*)t0row)[l];
        uint2 w1 = ((const uint2*)(x1 + (size_t)n * 32))[l];
        uint2 w2 = ((const uint2*)(x2 + (size_t)n * 32))[l];
        v2f b10 = unpack_bf16x2(w1.x), b11 = unpack_bf16x2(w1.y);
        v2f b20 = unpack_bf16x2(w2.x), b21 = unpack_bf16x2(w2.y);
        float4 r;
        r.x = x0.x + b10.x + b20.x + a0.x;
        r.y = x0.y + b10.y + b20.y + a0.y;
        r.z = x0.z + b11.x + b21.x + a1.x;
        r.w = x0.w + b11.y + b21.y + a1.y;
        rows[(size_t)w * 16 + l] = r;
    }
}

// gamma[b] = dot(rows[b], rows[BATCH+b]) / 16
__global__ __launch_bounds__(256) void dot_kernel(const float* __restrict__ rows,
                                                  float* __restrict__ out) {
    int t = blockIdx.x * 256 + threadIdx.x;
    int b = t >> 6;
    int lane = t & 63;
    float p = rows[(size_t)b * DIM + lane] * rows[(size_t)(BATCH + b) * DIM + lane];
#pragma unroll
    for (int o = 32; o > 0; o >>= 1) p += __shfl_down(p, o, 64);
    if (lane == 0) out[b] = p * (1.0f / 16.0f);
}

extern "C" void kernel_launch(void* const* d_in, const int* in_sizes, int n_in,
                              void* d_out, int out_size, void* d_ws, size_t ws_size,
                              hipStream_t stream) {
    const float* emb_user = (const float*)d_in[0];
    const float* emb_item = (const float*)d_in[1];
    const float* vals     = (const float*)d_in[2];
    const int*   src      = (const int*)d_in[3];
    const int*   dst      = (const int*)d_in[4];
    const int*   users    = (const int*)d_in[5];
    const int*   items    = (const int*)d_in[6];
    float* out = (float*)d_out;

    char* ws = (char*)d_ws;
    size_t off = 0;
    auto walloc = [&](size_t bytes) -> void* {
        void* p = ws + off;
        off += (bytes + 255) & ~(size_t)255;
        return p;
    };
    const size_t ROWB = (size_t)N_NODES * DIM * 2;                  // 19.2 MB
    uint* t0          = (uint*)walloc(ROWB);                        // bf16 x0
    uint* x1          = (uint*)walloc(ROWB);
    uint* x2          = (uint*)walloc(ROWB);
    int2* coarse      = (int2*)walloc((size_t)KB * ECAP * 8);       // 21.0 MB
    int*  gcur        = (int*) walloc((size_t)KB * 4);
    uint* rowinfo     = (uint*)walloc((size_t)N_NODES * 4);
    float4* rows      = (float4*)walloc((size_t)2 * BATCH * DIM * 4); // 2 MB

    hipMemsetAsync(gcur, 0, (size_t)KB * 4, stream);

    // Build: single-pass partition (+ fused conv), then in-place fine sort
    part_kernel<<<CHUNKS + CONVB, 1024, 0, stream>>>(
        src, dst, vals, gcur, coarse, emb_user, emb_item, (uint2*)t0);
    p4f_fine<<<KB, 1024, 0, stream>>>(coarse, gcur, rowinfo);

    // Layers 1,2 full; layer 3 batch-only + dot
    // 18750 node-waves (8 nodes/wave) -> 1.2M threads -> 4688 blocks (guarded)
    const int SPMM_BLOCKS = (N_NODES / 8 * 64 + 255) / 256;
    spmm_kernel<<<SPMM_BLOCKS, 256, 0, stream>>>(rowinfo, coarse, t0, x1);
    spmm_kernel<<<SPMM_BLOCKS, 256, 0, stream>>>(rowinfo, coarse, x1, x2);
    batch_row_kernel<<<(2 * BATCH) / 4, 256, 0, stream>>>(
        users, items, emb_user, emb_item, x1, x2, rowinfo, coarse, rows);
    dot_kernel<<<(BATCH * 64) / 256, 256, 0, stream>>>((const float*)rows, out);
}

// Round 5
// 243.994 us; speedup vs baseline: 1.1645x; 1.0321x over previous
//
#include <hip/hip_runtime.h>

// LightGCN propagation: 3x SpMM over fixed COO graph + batched dot epilogue.
// R18: part_kernel -> full LDS counting sort per chunk, coalesced output.
// R15-R17 profile: part stuck ~48-53us with ALL pipes idle (VALU 4%, HBM
// 22%, occ 55%) and WRITE_SIZE rising 46->54MB -> suspect = global write
// path: 2.4M random 8B stores (64 transactions per wave-store, partial-
// line RMW across blocks) + 65536 device-scope atomics packed in 16 cache
// lines. Now: pass1 returning-atomic rank (R17) -> block scan of 256-
// bucket hist -> edges staged SORTED in LDS (75KB payload + 9.4KB bucket
// ids) -> pass2 streams out: wave writes ~2 contiguous segments instead
// of 64 scatters. gcur padded to 1 counter/64B line (atomic line-serial).
// coarse layout & rowinfo unchanged -> p4f/spmm/batch/dot untouched.
// spmm (R16): 8 nodes/wave octets, cooperative 64B epair fetch, 8-deep
// row-gather MLP, near ~3.5TB/s random-128B-gather fabric ceiling.
// Fine sort in place per super-bucket (80KB LDS). Layer 3 batch-only.
// bf16 rows (R5).

#define N_USERS 50000
#define N_ITEMS 100000
#define N_NODES 150000
#define N_EDGES 2400000
#define DIM 64
#define BATCH 4096

#define CHUNKS 256
#define CHUNK_EDGES 9375   // 256*9375 = 2400000 exact
#define PPT 10             // ceil(9375/1024) edges per thread per pass
#define KB 256             // super-buckets
#define NPB 586            // nodes per bucket; 256*586 = 150016 >= N_NODES
#define ECAP 10240         // bucket capacity: mean 9375, sigma 97 -> +8.9 sigma
#define GSTR 16            // gcur stride: 1 counter per 64B line
#define CONVB 2344         // ceil(2400000 float4 / 1024)

typedef unsigned int uint;
typedef float v2f __attribute__((ext_vector_type(2)));

__device__ __forceinline__ uint pack_bf16(float a, float b) {
    uint ua = __float_as_uint(a), ub = __float_as_uint(b);
    ua = (ua + 0x7FFFu + ((ua >> 16) & 1u)) >> 16;   // RTNE
    ub = (ub + 0x7FFFu + ((ub >> 16) & 1u)) >> 16;
    return ua | (ub << 16);
}

__device__ __forceinline__ v2f unpack_bf16x2(uint w) {
    v2f r;
    r.x = __uint_as_float(w << 16);
    r.y = __uint_as_float(w & 0xFFFF0000u);
    return r;
}

// PART: blocks [0,CHUNKS): LDS counting sort of the chunk's 9375 edges by
// super-bucket, then coalesced segment write-out into reserved fat runs.
// Blocks [CHUNKS,..): fp32 -> bf16 concat t0.
__global__ __launch_bounds__(1024) void part_kernel(
        const int* __restrict__ src, const int* __restrict__ dstA,
        const float* __restrict__ vals, int* __restrict__ gcur,
        int2* __restrict__ coarse,
        const float* __restrict__ emb_user, const float* __restrict__ emb_item,
        uint2* __restrict__ t0) {
    int t = threadIdx.x;
    if (blockIdx.x >= CHUNKS) {
        int i = (blockIdx.x - CHUNKS) * 1024 + t;  // float4 index, 2.4M total
        if (i < N_NODES * DIM / 4) {
            const int userN4 = N_USERS * DIM / 4; // 800000
            float4 v;
            if (i < userN4) v = ((const float4*)emb_user)[i];
            else            v = ((const float4*)emb_item)[i - userN4];
            t0[i] = make_uint2(pack_bf16(v.x, v.y), pack_bf16(v.z, v.w));
        }
        return;
    }
    __shared__ int2 stage[CHUNK_EDGES];              // 75000 B sorted payload
    __shared__ unsigned char stage_b[CHUNK_EDGES];   // 9375 B bucket ids
    __shared__ int h[KB];
    __shared__ int hoff[KB];
    __shared__ int delta[KB];
    __shared__ int wsum4[4];
    int c = blockIdx.x;
    if (t < KB) h[t] = 0;
    __syncthreads();
    int base = c * CHUNK_EDGES;
    int d_c[PPT];
    int r_c[PPT];
#pragma unroll
    for (int u = 0; u < PPT; ++u) {
        int i = t + u * 1024;
        d_c[u] = 0;
        r_c[u] = 0;
        if (i < CHUNK_EDGES) {
            int d = dstA[base + i];
            d_c[u] = d;
            // returning atomic: rank within (chunk,bucket); independent ->
            // pipelined across the 10 unrolled iterations.
            r_c[u] = atomicAdd(&h[(int)((unsigned)d / NPB)], 1);
        }
    }
    __syncthreads();
    int lane = t & 63, wid = t >> 6;
    if (t < KB) {                     // 4-wave scan of 256 bucket counts
        int v = h[t];
        int incl = v;
#pragma unroll
        for (int o = 1; o < 64; o <<= 1) {
            int add = __shfl_up(incl, o, 64);
            if (lane >= o) incl += add;
        }
        hoff[t] = incl - v;
        if (lane == 63) wsum4[wid] = incl;
    }
    __syncthreads();
    if (t < 64) {
        int vv = (lane < 4) ? wsum4[lane] : 0;
        int inc2 = vv;
#pragma unroll
        for (int o = 1; o < 4; o <<= 1) {
            int add = __shfl_up(inc2, o, 64);
            if (lane >= o) inc2 += add;
        }
        if (lane < 4) wsum4[lane] = inc2 - vv;
    }
    __syncthreads();
    if (t < KB) {
        int off = hoff[t] + wsum4[t >> 6];           // chunk-local bucket start
        hoff[t] = off;
        int cb = atomicAdd(&gcur[t * GSTR], h[t]);   // reserve fat run (padded)
        delta[t] = t * ECAP + cb - off;              // sorted-pos -> coarse idx
    }
    __syncthreads();
    // pass 1.5: stage edges into sorted LDS slots
#pragma unroll
    for (int u = 0; u < PPT; ++u) {
        int i = t + u * 1024;
        if (i < CHUNK_EDGES) {
            int e = base + i;
            int d = d_c[u];
            int b = (int)((unsigned)d / NPB);
            int dl = d - b * NPB;
            int pos = hoff[b] + r_c[u];
            stage[pos] = make_int2(src[e] | (dl << 18), __float_as_int(vals[e]));
            stage_b[pos] = (unsigned char)b;
        }
    }
    __syncthreads();
    // pass 2: coalesced write-out (consecutive j -> consecutive coarse idx
    // within each per-bucket run of ~37 edges)
#pragma unroll
    for (int u = 0; u < PPT; ++u) {
        int j = t + u * 1024;
        if (j < CHUNK_EDGES) {
            int b = stage_b[j];
            int idx = j + delta[b];
            if (idx < (b + 1) * ECAP)                // overflow guard
                coarse[idx] = stage[j];
        }
    }
}

// P4F: per-super-bucket fine sort IN PLACE. Edges -> LDS (one read),
// histogram over 586 node counters, wave-shuffle scan, rowinfo emit,
// sorted scatter back into the same region.
__global__ __launch_bounds__(1024) void p4f_fine(int2* __restrict__ coarse,
                                                 const int* __restrict__ gcur,
                                                 uint* __restrict__ rowinfo) {
    __shared__ int2 eds[ECAP];        // 81920 B
    __shared__ int cnt[640];
    __shared__ int rs_[640];
    __shared__ int cur_[640];
    __shared__ int wsum[16];
    int k = blockIdx.x, t = threadIdx.x;
    int rbase = k * ECAP;
    int ne = min(gcur[k * GSTR], ECAP);
    for (int i = t; i < ne; i += 1024) eds[i] = coarse[rbase + i];
    if (t < 640) cnt[t] = 0;
    __syncthreads();
    for (int i = t; i < ne; i += 1024)
        atomicAdd(&cnt[eds[i].x >> 18], 1);
    __syncthreads();
    int wid = t >> 6, lane = t & 63;
    if (t < 640) {                    // waves 0..9 (640 = 10*64)
        int v = cnt[t];
        int incl = v;
#pragma unroll
        for (int o = 1; o < 64; o <<= 1) {
            int add = __shfl_up(incl, o, 64);
            if (lane >= o) incl += add;
        }
        rs_[t] = incl - v;
        if (lane == 63) wsum[wid] = incl;
    }
    __syncthreads();
    if (t < 64) {
        int vv = (lane < 10) ? wsum[lane] : 0;
        int inc2 = vv;
#pragma unroll
        for (int o = 1; o < 16; o <<= 1) {
            int add = __shfl_up(inc2, o, 64);
            if (lane >= o) inc2 += add;
        }
        if (lane < 10) wsum[lane] = inc2 - vv;
    }
    __syncthreads();
    if (t < 640) rs_[t] += wsum[wid];
    __syncthreads();
    int nodes0 = k * NPB;
    int nb = min(NPB, N_NODES - nodes0);
    if (t < nb)
        rowinfo[nodes0 + t] = (uint)(rbase + rs_[t]) | ((uint)cnt[t] << 22);
    if (t < 640) cur_[t] = rs_[t];
    __syncthreads();
    for (int i = t; i < ne; i += 1024) {
        int2 ev = eds[i];
        int dl = ev.x >> 18;
        int p = atomicAdd(&cur_[dl], 1);
        coarse[rbase + p] = make_int2(ev.x & 0x3FFFF, ev.y);   // strip dl
    }
}

// SpMM over bf16 rows (128B/row). R16 form: 8 nodes per wave, one octet
// (8 lanes x uint4 = full row) per node. Per round: octet cooperatively
// loads 8 epair entries (64B coalesced), shfl-broadcasts src/val, issues
// 8 independent row gathers, then FMAs. No cross-lane reduce; wave
// stores 1KB contiguous (8 rows).
__global__ __launch_bounds__(256) void spmm_kernel(
        const uint* __restrict__ rowinfo, const int2* __restrict__ epair,
        const uint* __restrict__ xin, uint* __restrict__ xout) {
    int wave = (blockIdx.x * 256 + threadIdx.x) >> 6;
    int lane = threadIdx.x & 63;
    int g = lane >> 3;                // octet id = node slot 0..7
    int l = lane & 7;                 // uint4 slot within row
    int n = wave * 8 + g;
    bool live = n < N_NODES;
    uint ri = live ? rowinfo[n] : 0u;
    int s = (int)(ri & 0x3FFFFFu);
    int e = live ? s + (int)(ri >> 22) : s;   // empty/dead: e==s skips loop
    int gbase = g * 8;
    v2f a0 = {0.f, 0.f}, a1 = {0.f, 0.f}, a2 = {0.f, 0.f}, a3 = {0.f, 0.f};
    for (int jb = s; jb < e; jb += 8) {
        int jl = jb + l;
        // cooperative 64B epair fetch; tail clamps to e-1 (same line, w=0)
        int2 ev = epair[jl < e ? jl : (e - 1)];
        float vw = (jl < e) ? __int_as_float(ev.y) : 0.f;
        int sx = ev.x;
        int srcs[8];
        float ws[8];
#pragma unroll
        for (int u = 0; u < 8; ++u) {
            srcs[u] = __shfl(sx, gbase + u, 64);
            ws[u]   = __shfl(vw, gbase + u, 64);
        }
        uint4 r[8];
#pragma unroll
        for (int u = 0; u < 8; ++u)
            r[u] = ((const uint4*)(xin + (size_t)srcs[u] * 32))[l];
#pragma unroll
        for (int u = 0; u < 8; ++u) {
            a0 += ws[u] * unpack_bf16x2(r[u].x);
            a1 += ws[u] * unpack_bf16x2(r[u].y);
            a2 += ws[u] * unpack_bf16x2(r[u].z);
            a3 += ws[u] * unpack_bf16x2(r[u].w);
        }
    }
    if (live) {
        uint4 o;
        o.x = pack_bf16(a0.x, a0.y);
        o.y = pack_bf16(a1.x, a1.y);
        o.z = pack_bf16(a2.x, a2.y);
        o.w = pack_bf16(a3.x, a3.y);
        ((uint4*)(xout + (size_t)n * 32))[l] = o;   // wave: 8 rows = 1KB contig
    }
}

// Layer-3 restricted to batch rows: one wave per batch node (2*BATCH waves).
// x3[n] = sum val*x2[src]; add x0 (fp32) + x1 + x2 (bf16); store fp32 row.
__global__ __launch_bounds__(256) void batch_row_kernel(
        const int* __restrict__ users, const int* __restrict__ items,
        const float* __restrict__ emb_user, const float* __restrict__ emb_item,
        const uint* __restrict__ x1, const uint* __restrict__ x2,
        const uint* __restrict__ rowinfo, const int2* __restrict__ epair,
        float4* __restrict__ rows) {
    int w = (blockIdx.x * 256 + threadIdx.x) >> 6;   // 0..2*BATCH-1
    int lane = threadIdx.x & 63;
    int g = lane >> 4;
    int l = lane & 15;        // uint2 slot: dims 4l..4l+3
    bool isU = w < BATCH;
    int b = isU ? w : w - BATCH;
    int idx = isU ? users[b] : items[b];
    int n = isU ? idx : N_USERS + idx;
    uint ri = rowinfo[n];
    int s = (int)(ri & 0x3FFFFFu);
    int e = s + (int)(ri >> 22);
    v2f a0 = {0.f, 0.f}, a1 = {0.f, 0.f};
    for (int j0 = s + g; j0 < e; j0 += 16) {
        int2 ev[4];
        float vv[4];
        uint2 rr[4];
#pragma unroll
        for (int u = 0; u < 4; ++u) {
            int j = j0 + 4 * u;
            bool p = (u == 0) || (j < e);
            ev[u] = epair[p ? j : j0];
            vv[u] = p ? __int_as_float(ev[u].y) : 0.f;
        }
#pragma unroll
        for (int u = 0; u < 4; ++u)
            rr[u] = ((const uint2*)(x2 + (size_t)ev[u].x * 32))[l];
#pragma unroll
        for (int u = 0; u < 4; ++u) {
            a0 += vv[u] * unpack_bf16x2(rr[u].x);
            a1 += vv[u] * unpack_bf16x2(rr[u].y);
        }
    }
#pragma unroll
    for (int off = 16; off < 64; off <<= 1) {
        a0.x += __shfl_xor(a0.x, off, 64);
        a0.y += __shfl_xor(a0.y, off, 64);
        a1.x += __shfl_xor(a1.x, off, 64);
        a1.y += __shfl_xor(a1.y, off, 64);
    }
    if (g == 0) {
        const float* t0row = isU ? (emb_user + (size_t)idx * DIM)
                                 : (emb_item + (size_t)idx * DIM);
        float4 x0 = ((const float4*)t0row)[l];
        uint2 w1 = ((const uint2*)(x1 + (size_t)n * 32))[l];
        uint2 w2 = ((const uint2*)(x2 + (size_t)n * 32))[l];
        v2f b10 = unpack_bf16x2(w1.x), b11 = unpack_bf16x2(w1.y);
        v2f b20 = unpack_bf16x2(w2.x), b21 = unpack_bf16x2(w2.y);
        float4 r;
        r.x = x0.x + b10.x + b20.x + a0.x;
        r.y = x0.y + b10.y + b20.y + a0.y;
        r.z = x0.z + b11.x + b21.x + a1.x;
        r.w = x0.w + b11.y + b21.y + a1.y;
        rows[(size_t)w * 16 + l] = r;
    }
}

// gamma[b] = dot(rows[b], rows[BATCH+b]) / 16
__global__ __launch_bounds__(256) void dot_kernel(const float* __restrict__ rows,
                                                  float* __restrict__ out) {
    int t = blockIdx.x * 256 + threadIdx.x;
    int b = t >> 6;
    int lane = t & 63;
    float p = rows[(size_t)b * DIM + lane] * rows[(size_t)(BATCH + b) * DIM + lane];
#pragma unroll
    for (int o = 32; o > 0; o >>= 1) p += __shfl_down(p, o, 64);
    if (lane == 0) out[b] = p * (1.0f / 16.0f);
}

extern "C" void kernel_launch(void* const* d_in, const int* in_sizes, int n_in,
                              void* d_out, int out_size, void* d_ws, size_t ws_size,
                              hipStream_t stream) {
    const float* emb_user = (const float*)d_in[0];
    const float* emb_item = (const float*)d_in[1];
    const float* vals     = (const float*)d_in[2];
    const int*   src      = (const int*)d_in[3];
    const int*   dst      = (const int*)d_in[4];
    const int*   users    = (const int*)d_in[5];
    const int*   items    = (const int*)d_in[6];
    float* out = (float*)d_out;

    char* ws = (char*)d_ws;
    size_t off = 0;
    auto walloc = [&](size_t bytes) -> void* {
        void* p = ws + off;
        off += (bytes + 255) & ~(size_t)255;
        return p;
    };
    const size_t ROWB = (size_t)N_NODES * DIM * 2;                  // 19.2 MB
    uint* t0          = (uint*)walloc(ROWB);                        // bf16 x0
    uint* x1          = (uint*)walloc(ROWB);
    uint* x2          = (uint*)walloc(ROWB);
    int2* coarse      = (int2*)walloc((size_t)KB * ECAP * 8);       // 21.0 MB
    int*  gcur        = (int*) walloc((size_t)KB * GSTR * 4);       // padded
    uint* rowinfo     = (uint*)walloc((size_t)N_NODES * 4);
    float4* rows      = (float4*)walloc((size_t)2 * BATCH * DIM * 4); // 2 MB

    hipMemsetAsync(gcur, 0, (size_t)KB * GSTR * 4, stream);

    // Build: single-pass partition (+ fused conv), then in-place fine sort
    part_kernel<<<CHUNKS + CONVB, 1024, 0, stream>>>(
        src, dst, vals, gcur, coarse, emb_user, emb_item, (uint2*)t0);
    p4f_fine<<<KB, 1024, 0, stream>>>(coarse, gcur, rowinfo);

    // Layers 1,2 full; layer 3 batch-only + dot
    // 18750 node-waves (8 nodes/wave) -> 1.2M threads -> 4688 blocks (guarded)
    const int SPMM_BLOCKS = (N_NODES / 8 * 64 + 255) / 256;
    spmm_kernel<<<SPMM_BLOCKS, 256, 0, stream>>>(rowinfo, coarse, t0, x1);
    spmm_kernel<<<SPMM_BLOCKS, 256, 0, stream>>>(rowinfo, coarse, x1, x2);
    batch_row_kernel<<<(2 * BATCH) / 4, 256, 0, stream>>>(
        users, items, emb_user, emb_item, x1, x2, rowinfo, coarse, rows);
    dot_kernel<<<(BATCH * 64) / 256, 256, 0, stream>>>((const float*)rows, out);
}